// Round 11
// baseline (115.969 us; speedup 1.0000x reference)
//
#include <hip/hip_runtime.h>

#define LRELU(v) ((v) > 0.f ? (v) : 0.2f * (v))
#define MAXNB 512        // dst-buckets of 128 nodes; src|dst<<16 pack needs N <= 65536
#define BCAP 8192        // edge capacity per bucket: mean 4092, sigma 64 -> huge headroom
#define WCAP (BCAP + 128)  // ssrc window = edges + up to 128 self loops
#define MS_CHUNK 8192

// ---------------------------------------------------------------------------
// k_h1: per-node packed record rec[n*8] = {as1[0..3], x0, x1, x2, pad} (32B).
// Block 0 additionally inits bucket cursors and runs the dtype probe (ballot).
__global__ void __launch_bounds__(256) k_h1(const float* __restrict__ x,
                                            const float* __restrict__ W1,
                                            const float* __restrict__ aws,
                                            const float* __restrict__ awd,
                                            const int* __restrict__ ei,
                                            float* __restrict__ rec,
                                            float* __restrict__ ad1,
                                            int* __restrict__ gcur,
                                            int* __restrict__ flag, int nb, int N) {
    int t = threadIdx.x;
    if (blockIdx.x == 0) {
        for (int i = t; i < nb; i += 256) gcur[i] = i * BCAP;
        if (t < 64) {
            int a = ei[2 * t + 1];
            int b = ei[2 * (t + 64) + 1];
            unsigned long long any = __ballot((a | b) != 0);
            if (t == 0) *flag = (any == 0ull) ? 1 : 0;
        }
    }
    int n = blockIdx.x * 2 + (t >> 7);
    int f = t & 127;
    if (n >= N) return;
    float x0 = x[n * 3 + 0], x1 = x[n * 3 + 1], x2 = x[n * 3 + 2];
    float h = fmaf(x0, W1[f], fmaf(x1, W1[128 + f], x2 * W1[256 + f]));
    float ps = h * aws[f];
    float pd = h * awd[f];
#pragma unroll
    for (int m = 1; m < 32; m <<= 1) {
        ps += __shfl_xor(ps, m);
        pd += __shfl_xor(pd, m);
    }
    int head = f >> 5;
    if ((f & 31) == 0) {
        rec[n * 8 + head] = ps;
        ad1[n * 4 + head] = pd;
    }
    if (f < 3) rec[n * 8 + 4 + f] = x[n * 3 + f];
}

// ---------------------------------------------------------------------------
// Single-pass multisplit into FIXED per-bucket windows (no histogram pre-pass).
__global__ void __launch_bounds__(256) k_msplit(const int* __restrict__ ei, long long E,
                                                const int* __restrict__ flag,
                                                int* __restrict__ gcur,
                                                unsigned* __restrict__ bstage) {
    __shared__ unsigned stage[MS_CHUNK];
    __shared__ int h[MAXNB], lbase[MAXNB], lcur[MAXNB];
    int t = threadIdx.x;
    for (int i = t; i < MAXNB; i += 256) h[i] = 0;
    __syncthreads();
    long long beg = (long long)blockIdx.x * MS_CHUNK;
    int cnt = (int)min((long long)MS_CHUNK, E - beg);
    int is64 = *flag;
    for (int k = t; k < cnt; k += 256) {
        long long i = beg + k;
        int s, d;
        if (is64) {
            s = (int)((const long long*)ei)[i];
            d = (int)((const long long*)ei)[E + i];
        } else {
            s = ei[i];
            d = ei[E + i];
        }
        stage[k] = (unsigned)s | ((unsigned)d << 16);
        atomicAdd(&h[d >> 7], 1);
    }
    __syncthreads();
    for (int b = t; b < MAXNB; b += 256) {
        lcur[b] = 0;
        if (h[b]) lbase[b] = atomicAdd(&gcur[b], h[b]);
    }
    __syncthreads();
    for (int k = t; k < cnt; k += 256) {
        unsigned pk = stage[k];
        int b = (int)(pk >> 23);  // dst >> 7
        int idx = lbase[b] + atomicAdd(&lcur[b], 1);
        if (idx < (b + 1) * BCAP) bstage[idx] = pk;  // guard (never fires)
    }
}

// ---------------------------------------------------------------------------
// FUSED per-bucket: (B) CSR build for this bucket -> ssrc/beg/end, then
// block-local barrier, then (C) layer-1 rank-3 aggregate + W1 expand + ELU +
// W2 matmul + alpha2 for the SAME 128 nodes. The former inter-kernel barrier
// (all buckets built before any aggregate) becomes block-local; ssrc reads in
// phase C are same-CU L1/L2-hot. 512 threads; ~30KB LDS -> 4 blocks/CU, all
// 391 blocks co-resident.
__global__ void __launch_bounds__(512) k_b1(const unsigned* __restrict__ bstage,
                                            const int* __restrict__ gcur,
                                            const float* __restrict__ rec,
                                            const float* __restrict__ ad1,
                                            const float* __restrict__ W1,
                                            const float* __restrict__ b1,
                                            const float* __restrict__ W2,
                                            const float* __restrict__ aws2,
                                            const float* __restrict__ awd2,
                                            int* __restrict__ beg,
                                            int* __restrict__ endo,
                                            int* __restrict__ ssrc,
                                            float* __restrict__ h2w,
                                            float* __restrict__ as2,
                                            float* __restrict__ ad2, int N) {
    __shared__ int nc[128], sscan[128], lcur[128], begL[128], endL[128];
    __shared__ float sW1[384], sb1[128], sW2[128 * 16];
    __shared__ float shx[32][132];  // epilogue tile (+4 pad)

    int b = blockIdx.x, t = threadIdx.x;
    int node0 = b * 128;
    int base = b * BCAP;
    int cnt = min(gcur[b], base + BCAP) - base;

    // stage weights (consumed after the phase-C barrier)
    for (int i = t; i < 384; i += 512) sW1[i] = W1[i];
    for (int i = t; i < 2048; i += 512) sW2[i] = W2[i];
    if (t < 128) { sb1[t] = b1[t]; nc[t] = 0; }
    __syncthreads();

    // ---- phase B: per-node histogram -> scan -> self-loops + edge scatter
    for (int i = t; i < cnt; i += 512)
        atomicAdd(&nc[(bstage[base + i] >> 16) & 127], 1);
    __syncthreads();
    int node = node0 + (t & 127);
    int v = 0;
    if (t < 128) {
        v = (node < N) ? nc[t] + 1 : 0;  // +1 self loop
        sscan[t] = v;
    }
    __syncthreads();
#pragma unroll
    for (int off = 1; off < 128; off <<= 1) {
        int add = (t < 128 && t >= off) ? sscan[t - off] : 0;
        __syncthreads();
        if (t < 128) sscan[t] += add;
        __syncthreads();
    }
    int sbase = b * WCAP;  // private padded window
    if (t < 128 && node < N) {
        int o = sbase + sscan[t] - v;  // exclusive
        beg[node] = o;
        endo[node] = o + v;
        begL[t] = o;
        endL[t] = o + v;
        ssrc[o] = node;  // self loop first
        lcur[t] = o + 1;
    }
    __syncthreads();
    for (int i = t; i < cnt; i += 512) {
        unsigned pk = bstage[base + i];
        int p = atomicAdd(&lcur[(pk >> 16) & 127], 1);
        ssrc[p] = (int)(pk & 0xFFFFu);
    }
    __syncthreads();  // ssrc window complete (same-CU L1/L2-hot below)

    // ---- phase C: aggregate 128 nodes in 4 tiles of 32 (16 edge-lanes each)
    int nl = t >> 4;          // 0..31 node-in-tile
    int g = t & 15;           // edge slot / epilogue lane
#pragma unroll
    for (int tile = 0; tile < 4; ++tile) {
        int d = tile * 32 + nl;
        int n = node0 + d;
        float t0_0 = 0.f, t1_0 = 0.f, t2_0 = 0.f, ds_0 = 0.f;
        float t0_1 = 0.f, t1_1 = 0.f, t2_1 = 0.f, ds_1 = 0.f;
        float t0_2 = 0.f, t1_2 = 0.f, t2_2 = 0.f, ds_2 = 0.f;
        float t0_3 = 0.f, t1_3 = 0.f, t2_3 = 0.f, ds_3 = 0.f;
        if (n < N) {
            int e0 = begL[d], e1 = endL[d];
            const float4 adv = *(const float4*)(ad1 + (size_t)n * 4);
            for (int e = e0 + g; e < e1; e += 16) {
                int s = ssrc[e];
                const float4 a4 = *(const float4*)(rec + (size_t)s * 8);
                const float4 x4 = *(const float4*)(rec + (size_t)s * 8 + 4);
                float w;
                w = __expf(LRELU(a4.x + adv.x));
                ds_0 += w; t0_0 = fmaf(w, x4.x, t0_0); t1_0 = fmaf(w, x4.y, t1_0); t2_0 = fmaf(w, x4.z, t2_0);
                w = __expf(LRELU(a4.y + adv.y));
                ds_1 += w; t0_1 = fmaf(w, x4.x, t0_1); t1_1 = fmaf(w, x4.y, t1_1); t2_1 = fmaf(w, x4.z, t2_1);
                w = __expf(LRELU(a4.z + adv.z));
                ds_2 += w; t0_2 = fmaf(w, x4.x, t0_2); t1_2 = fmaf(w, x4.y, t1_2); t2_2 = fmaf(w, x4.z, t2_2);
                w = __expf(LRELU(a4.w + adv.w));
                ds_3 += w; t0_3 = fmaf(w, x4.x, t0_3); t1_3 = fmaf(w, x4.y, t1_3); t2_3 = fmaf(w, x4.z, t2_3);
            }
        }
#pragma unroll
        for (int msk = 1; msk < 16; msk <<= 1) {
            t0_0 += __shfl_xor(t0_0, msk); t1_0 += __shfl_xor(t1_0, msk);
            t2_0 += __shfl_xor(t2_0, msk); ds_0 += __shfl_xor(ds_0, msk);
            t0_1 += __shfl_xor(t0_1, msk); t1_1 += __shfl_xor(t1_1, msk);
            t2_1 += __shfl_xor(t2_1, msk); ds_1 += __shfl_xor(ds_1, msk);
            t0_2 += __shfl_xor(t0_2, msk); t1_2 += __shfl_xor(t1_2, msk);
            t2_2 += __shfl_xor(t2_2, msk); ds_2 += __shfl_xor(ds_2, msk);
            t0_3 += __shfl_xor(t0_3, msk); t1_3 += __shfl_xor(t1_3, msk);
            t2_3 += __shfl_xor(t2_3, msk); ds_3 += __shfl_xor(ds_3, msk);
        }
        // head selection: lane g expands features f=g*8..g*8+7 of head g>>2
        int hs = g >> 2;
        float u0 = hs == 0 ? t0_0 : hs == 1 ? t0_1 : hs == 2 ? t0_2 : t0_3;
        float u1 = hs == 0 ? t1_0 : hs == 1 ? t1_1 : hs == 2 ? t1_2 : t1_3;
        float u2 = hs == 0 ? t2_0 : hs == 1 ? t2_1 : hs == 2 ? t2_2 : t2_3;
        float dsv = hs == 0 ? ds_0 : hs == 1 ? ds_1 : hs == 2 ? ds_2 : ds_3;
        float ui = 1.f / fmaxf(dsv, 1e-16f);

        int f0 = g * 8;
#pragma unroll
        for (int j = 0; j < 8; ++j) {
            int f = f0 + j;
            float o = fmaf(fmaf(u0, sW1[f], fmaf(u1, sW1[128 + f], u2 * sW1[256 + f])), ui, sb1[f]);
            shx[nl][f] = (o > 0.f) ? o : __expf(o) - 1.f;  // ELU
        }
        __syncthreads();

        // W2 matmul: thread (nl, c) -> h2w[n, c]; + alpha2 reduce
        int c = g;
        const float4* hr4 = (const float4*)shx[nl];
        float acc = 0.f;
#pragma unroll 8
        for (int k4 = 0; k4 < 32; ++k4) {
            float4 hv = hr4[k4];
            acc = fmaf(hv.x, sW2[(k4 * 4 + 0) * 16 + c], acc);
            acc = fmaf(hv.y, sW2[(k4 * 4 + 1) * 16 + c], acc);
            acc = fmaf(hv.z, sW2[(k4 * 4 + 2) * 16 + c], acc);
            acc = fmaf(hv.w, sW2[(k4 * 4 + 3) * 16 + c], acc);
        }
        if (n < N) {
            h2w[(size_t)n * 16 + c] = acc;
            float ps = acc * aws2[c];
            float pd = acc * awd2[c];
#pragma unroll
            for (int m = 1; m < 16; m <<= 1) {
                ps += __shfl_xor(ps, m);
                pd += __shfl_xor(pd, m);
            }
            if (c == 0) {
                as2[n] = ps;
                ad2[n] = pd;
            }
        }
        __syncthreads();  // shx reused next tile
    }
}

// ---------------------------------------------------------------------------
// Layer-2 softmax+aggregate -> d_out. 16 lanes/node (slot(4) x c-quad(4)),
// single pass (no max), 16 nodes per 256-thread block. No LDS, no barriers.
__global__ void __launch_bounds__(256) k_gat2(const float* __restrict__ h2w,
                                              const float* __restrict__ as2,
                                              const float* __restrict__ ad2,
                                              const int* __restrict__ beg,
                                              const int* __restrict__ endo,
                                              const int* __restrict__ ssrc,
                                              const float* __restrict__ b2,
                                              float* __restrict__ out, int N) {
    int t = threadIdx.x;
    int nl = t >> 4, g = t & 15;
    int n = blockIdx.x * 16 + nl;
    if (n >= N) return;
    int slot = g >> 2, c4 = g & 3;
    int e0 = beg[n], e1 = endo[n];
    float ad = ad2[n];

    float4 acc = {0.f, 0.f, 0.f, 0.f};
    float ds = 0.f;
    for (int e = e0 + slot; e < e1; e += 4) {
        int s = ssrc[e];
        float w = __expf(LRELU(as2[s] + ad));
        ds += w;
        const float4 hv = *(const float4*)(h2w + (size_t)s * 16 + c4 * 4);
        acc.x = fmaf(w, hv.x, acc.x);
        acc.y = fmaf(w, hv.y, acc.y);
        acc.z = fmaf(w, hv.z, acc.z);
        acc.w = fmaf(w, hv.w, acc.w);
    }
#pragma unroll
    for (int msk = 4; msk < 16; msk <<= 1) {
        acc.x += __shfl_xor(acc.x, msk);
        acc.y += __shfl_xor(acc.y, msk);
        acc.z += __shfl_xor(acc.z, msk);
        acc.w += __shfl_xor(acc.w, msk);
        ds += __shfl_xor(ds, msk);
    }
    if (slot == 0) {
        float inv = 1.f / fmaxf(ds, 1e-16f);
        float4 bq = ((const float4*)b2)[c4];
        float4 o;
        o.x = fmaf(acc.x, inv, bq.x);
        o.y = fmaf(acc.y, inv, bq.y);
        o.z = fmaf(acc.z, inv, bq.z);
        o.w = fmaf(acc.w, inv, bq.w);
        *(float4*)(out + (size_t)n * 16 + c4 * 4) = o;
    }
}

// ---------------------------------------------------------------------------
extern "C" void kernel_launch(void* const* d_in, const int* in_sizes, int n_in,
                              void* d_out, int out_size, void* d_ws, size_t ws_size,
                              hipStream_t stream) {
    const float* x    = (const float*)d_in[0];
    const int*   ei   = (const int*)d_in[1];
    const float* W1   = (const float*)d_in[2];
    const float* aws1 = (const float*)d_in[3];
    const float* awd1 = (const float*)d_in[4];
    const float* b1   = (const float*)d_in[5];
    const float* W2   = (const float*)d_in[6];
    const float* aws2 = (const float*)d_in[7];
    const float* awd2 = (const float*)d_in[8];
    const float* b2   = (const float*)d_in[9];
    float* out = (float*)d_out;

    const int N = in_sizes[0] / 3;            // 50000
    const long long E = in_sizes[1] / 2;      // 1600000
    const int NB = (N + 127) / 128;           // 391 dst-buckets

    char* w = (char*)d_ws;
    auto alloc = [&](size_t bytes) {
        char* p = w;
        w += (bytes + 255) & ~(size_t)255;
        return p;
    };
    float*    rec    = (float*)alloc((size_t)N * 8 * 4);        // {as1[4], x0,x1,x2,pad}
    float*    ad1    = (float*)alloc((size_t)N * 4 * 4);
    float*    h2w    = (float*)alloc((size_t)N * 16 * 4);
    float*    as2    = (float*)alloc((size_t)N * 4);
    float*    ad2    = (float*)alloc((size_t)N * 4);
    int*      beg    = (int*)alloc((size_t)N * 4);
    int*      endo   = (int*)alloc((size_t)N * 4);
    int*      ssrc   = (int*)alloc((size_t)NB * WCAP * 4);      // padded windows
    unsigned* bstage = (unsigned*)alloc((size_t)NB * BCAP * 4); // padded windows
    int*      gcur   = (int*)alloc((size_t)NB * 4);
    int*      flag   = (int*)alloc(4);

    // 1) h1 records (+ gcur init + dtype probe in block 0)
    k_h1<<<(N + 1) / 2, 256, 0, stream>>>(x, W1, aws1, awd1, ei, rec, ad1,
                                          gcur, flag, NB, N);
    // 2) single-pass multisplit into fixed bucket windows
    k_msplit<<<(int)((E + MS_CHUNK - 1) / MS_CHUNK), 256, 0, stream>>>(ei, E, flag, gcur, bstage);
    // 3) fused per-bucket CSR build + layer-1 aggregate + W1/ELU/W2/alpha2
    k_b1<<<NB, 512, 0, stream>>>(bstage, gcur, rec, ad1, W1, b1, W2,
                                 aws2, awd2, beg, endo, ssrc, h2w, as2, ad2, N);
    // 4) layer-2 aggregate -> out
    k_gat2<<<(N + 15) / 16, 256, 0, stream>>>(h2w, as2, ad2, beg, endo, ssrc, b2, out, N);
}

// Round 12
// 108.997 us; speedup vs baseline: 1.0640x; 1.0640x over previous
//
#include <hip/hip_runtime.h>

#define LRELU(v) ((v) > 0.f ? (v) : 0.2f * (v))
#define MAXNB 512        // dst-buckets of 128 nodes; src|dst<<16 pack needs N <= 65536
#define BCAP 8192        // edge capacity per bucket: mean 4092, sigma 64 -> huge headroom
#define WCAP (BCAP + 128)  // ssrc window = edges + up to 128 self loops
#define MS_CHUNK 8192

// ---------------------------------------------------------------------------
// k_h1: per-node packed record rec[n*8] = {as1[0..3], x0, x1, x2, pad} (32B).
// Block 0 additionally inits bucket cursors and runs the dtype probe (ballot).
__global__ void __launch_bounds__(256) k_h1(const float* __restrict__ x,
                                            const float* __restrict__ W1,
                                            const float* __restrict__ aws,
                                            const float* __restrict__ awd,
                                            const int* __restrict__ ei,
                                            float* __restrict__ rec,
                                            float* __restrict__ ad1,
                                            int* __restrict__ gcur,
                                            int* __restrict__ flag, int nb, int N) {
    int t = threadIdx.x;
    if (blockIdx.x == 0) {
        for (int i = t; i < nb; i += 256) gcur[i] = i * BCAP;
        if (t < 64) {
            int a = ei[2 * t + 1];
            int b = ei[2 * (t + 64) + 1];
            unsigned long long any = __ballot((a | b) != 0);
            if (t == 0) *flag = (any == 0ull) ? 1 : 0;
        }
    }
    int n = blockIdx.x * 2 + (t >> 7);
    int f = t & 127;
    if (n >= N) return;
    float x0 = x[n * 3 + 0], x1 = x[n * 3 + 1], x2 = x[n * 3 + 2];
    float h = fmaf(x0, W1[f], fmaf(x1, W1[128 + f], x2 * W1[256 + f]));
    float ps = h * aws[f];
    float pd = h * awd[f];
#pragma unroll
    for (int m = 1; m < 32; m <<= 1) {
        ps += __shfl_xor(ps, m);
        pd += __shfl_xor(pd, m);
    }
    int head = f >> 5;
    if ((f & 31) == 0) {
        rec[n * 8 + head] = ps;
        ad1[n * 4 + head] = pd;
    }
    if (f < 3) rec[n * 8 + 4 + f] = x[n * 3 + f];
}

// ---------------------------------------------------------------------------
// Single-pass multisplit into FIXED per-bucket windows (no histogram pre-pass).
__global__ void __launch_bounds__(256) k_msplit(const int* __restrict__ ei, long long E,
                                                const int* __restrict__ flag,
                                                int* __restrict__ gcur,
                                                unsigned* __restrict__ bstage) {
    __shared__ unsigned stage[MS_CHUNK];
    __shared__ int h[MAXNB], lbase[MAXNB], lcur[MAXNB];
    int t = threadIdx.x;
    for (int i = t; i < MAXNB; i += 256) h[i] = 0;
    __syncthreads();
    long long beg = (long long)blockIdx.x * MS_CHUNK;
    int cnt = (int)min((long long)MS_CHUNK, E - beg);
    int is64 = *flag;
    for (int k = t; k < cnt; k += 256) {
        long long i = beg + k;
        int s, d;
        if (is64) {
            s = (int)((const long long*)ei)[i];
            d = (int)((const long long*)ei)[E + i];
        } else {
            s = ei[i];
            d = ei[E + i];
        }
        stage[k] = (unsigned)s | ((unsigned)d << 16);
        atomicAdd(&h[d >> 7], 1);
    }
    __syncthreads();
    for (int b = t; b < MAXNB; b += 256) {
        lcur[b] = 0;
        if (h[b]) lbase[b] = atomicAdd(&gcur[b], h[b]);
    }
    __syncthreads();
    for (int k = t; k < cnt; k += 256) {
        unsigned pk = stage[k];
        int b = (int)(pk >> 23);  // dst >> 7
        int idx = lbase[b] + atomicAdd(&lcur[b], 1);
        if (idx < (b + 1) * BCAP) bstage[idx] = pk;  // guard (never fires)
    }
}

// ---------------------------------------------------------------------------
// Per-bucket: node histogram -> 128-wide LDS scan -> beg/end + self-loops ->
// scatter edges into the bucket's private padded ssrc window.
__global__ void __launch_bounds__(256) k_bucket(const unsigned* __restrict__ bstage,
                                                const int* __restrict__ gcur,
                                                int* __restrict__ beg,
                                                int* __restrict__ endo,
                                                int* __restrict__ ssrc, int N) {
    __shared__ int nc[128];
    __shared__ int sscan[128];
    __shared__ int lcur[128];
    int b = blockIdx.x, t = threadIdx.x;
    if (t < 128) nc[t] = 0;
    __syncthreads();
    int base = b * BCAP;
    int c = min(gcur[b], (b + 1) * BCAP) - base;
    for (int i = t; i < c; i += 256)
        atomicAdd(&nc[(bstage[base + i] >> 16) & 127], 1);
    __syncthreads();
    int node = b * 128 + (t & 127);
    int v = 0;
    if (t < 128) {
        v = (node < N) ? nc[t] + 1 : 0;  // +1 self loop
        sscan[t] = v;
    }
    __syncthreads();
#pragma unroll
    for (int off = 1; off < 128; off <<= 1) {
        int add = (t < 128 && t >= off) ? sscan[t - off] : 0;
        __syncthreads();
        if (t < 128) sscan[t] += add;
        __syncthreads();
    }
    int sbase = b * WCAP;  // private padded window
    if (t < 128 && node < N) {
        int o = sbase + sscan[t] - v;  // exclusive
        beg[node] = o;
        endo[node] = o + v;
        ssrc[o] = node;  // self loop first
        lcur[t] = o + 1;
    }
    __syncthreads();
    for (int i = t; i < c; i += 256) {
        unsigned pk = bstage[base + i];
        int p = atomicAdd(&lcur[(pk >> 16) & 127], 1);
        ssrc[p] = (int)(pk & 0xFFFFu);
    }
}

// ---------------------------------------------------------------------------
// FUSED layer-1 aggregate (rank-3, single pass, no max) + W1 expand + ELU +
// W2 matmul + alpha2. 256 threads = 16 nodes x 16 edge-slot lanes.
// Edge loop is software-pipelined 2-wide: both ssrc reads issue together,
// then all 4 rec float4s -- one latency chain instead of two (k_b1 evidence:
// VALUBusy 19%, HBM 3%, occupancy 26% => latency-bound dependent gathers).
__global__ void __launch_bounds__(256) k_gat1w(const float* __restrict__ rec,
                                               const float* __restrict__ ad1,
                                               const int* __restrict__ beg,
                                               const int* __restrict__ endo,
                                               const int* __restrict__ ssrc,
                                               const float* __restrict__ W1,
                                               const float* __restrict__ b1,
                                               const float* __restrict__ W2,
                                               const float* __restrict__ aws2,
                                               const float* __restrict__ awd2,
                                               float* __restrict__ h2w,
                                               float* __restrict__ as2,
                                               float* __restrict__ ad2, int N) {
    __shared__ float sW1[384], sb1[128], sW2[128 * 16];
    __shared__ float shx[16][132];  // +4 pad
    int t = threadIdx.x;
    for (int i = t; i < 384; i += 256) sW1[i] = W1[i];
    if (t < 128) sb1[t] = b1[t];
    for (int i = t; i < 2048; i += 256) sW2[i] = W2[i];

    int nl = t >> 4;          // node-local 0..15
    int g = t & 15;           // edge slot within node group
    int n = blockIdx.x * 16 + nl;

    float t0_0 = 0.f, t1_0 = 0.f, t2_0 = 0.f, ds_0 = 0.f;
    float t0_1 = 0.f, t1_1 = 0.f, t2_1 = 0.f, ds_1 = 0.f;
    float t0_2 = 0.f, t1_2 = 0.f, t2_2 = 0.f, ds_2 = 0.f;
    float t0_3 = 0.f, t1_3 = 0.f, t2_3 = 0.f, ds_3 = 0.f;
    if (n < N) {
        int e0 = beg[n], e1 = endo[n];
        const float4 adv = *(const float4*)(ad1 + (size_t)n * 4);  // broadcast
        for (int e = e0 + g; e < e1; e += 32) {
            // two edges per iteration: independent load chains
            int sA = ssrc[e];
            bool vB = (e + 16) < e1;
            int sB = vB ? ssrc[e + 16] : sA;  // dup addr when invalid (masked)
            const float4 aA = *(const float4*)(rec + (size_t)sA * 8);
            const float4 xA = *(const float4*)(rec + (size_t)sA * 8 + 4);
            const float4 aB = *(const float4*)(rec + (size_t)sB * 8);
            const float4 xB = *(const float4*)(rec + (size_t)sB * 8 + 4);
            float kB = vB ? 1.f : 0.f;
            float w;
            w = __expf(LRELU(aA.x + adv.x));
            ds_0 += w; t0_0 = fmaf(w, xA.x, t0_0); t1_0 = fmaf(w, xA.y, t1_0); t2_0 = fmaf(w, xA.z, t2_0);
            w = __expf(LRELU(aA.y + adv.y));
            ds_1 += w; t0_1 = fmaf(w, xA.x, t0_1); t1_1 = fmaf(w, xA.y, t1_1); t2_1 = fmaf(w, xA.z, t2_1);
            w = __expf(LRELU(aA.z + adv.z));
            ds_2 += w; t0_2 = fmaf(w, xA.x, t0_2); t1_2 = fmaf(w, xA.y, t1_2); t2_2 = fmaf(w, xA.z, t2_2);
            w = __expf(LRELU(aA.w + adv.w));
            ds_3 += w; t0_3 = fmaf(w, xA.x, t0_3); t1_3 = fmaf(w, xA.y, t1_3); t2_3 = fmaf(w, xA.z, t2_3);

            w = kB * __expf(LRELU(aB.x + adv.x));
            ds_0 += w; t0_0 = fmaf(w, xB.x, t0_0); t1_0 = fmaf(w, xB.y, t1_0); t2_0 = fmaf(w, xB.z, t2_0);
            w = kB * __expf(LRELU(aB.y + adv.y));
            ds_1 += w; t0_1 = fmaf(w, xB.x, t0_1); t1_1 = fmaf(w, xB.y, t1_1); t2_1 = fmaf(w, xB.z, t2_1);
            w = kB * __expf(LRELU(aB.z + adv.z));
            ds_2 += w; t0_2 = fmaf(w, xB.x, t0_2); t1_2 = fmaf(w, xB.y, t1_2); t2_2 = fmaf(w, xB.z, t2_2);
            w = kB * __expf(LRELU(aB.w + adv.w));
            ds_3 += w; t0_3 = fmaf(w, xB.x, t0_3); t1_3 = fmaf(w, xB.y, t1_3); t2_3 = fmaf(w, xB.z, t2_3);
        }
    }
    // reduce all 16 partials across the 16-lane group (xor stays in-group)
#pragma unroll
    for (int msk = 1; msk < 16; msk <<= 1) {
        t0_0 += __shfl_xor(t0_0, msk); t1_0 += __shfl_xor(t1_0, msk);
        t2_0 += __shfl_xor(t2_0, msk); ds_0 += __shfl_xor(ds_0, msk);
        t0_1 += __shfl_xor(t0_1, msk); t1_1 += __shfl_xor(t1_1, msk);
        t2_1 += __shfl_xor(t2_1, msk); ds_1 += __shfl_xor(ds_1, msk);
        t0_2 += __shfl_xor(t0_2, msk); t1_2 += __shfl_xor(t1_2, msk);
        t2_2 += __shfl_xor(t2_2, msk); ds_2 += __shfl_xor(ds_2, msk);
        t0_3 += __shfl_xor(t0_3, msk); t1_3 += __shfl_xor(t1_3, msk);
        t2_3 += __shfl_xor(t2_3, msk); ds_3 += __shfl_xor(ds_3, msk);
    }
    // head selection: lane g expands features f=g*8..g*8+7 of head g>>2
    // (constant-index ternary chain -> cndmask, no scratch)
    int hs = g >> 2;
    float u0 = hs == 0 ? t0_0 : hs == 1 ? t0_1 : hs == 2 ? t0_2 : t0_3;
    float u1 = hs == 0 ? t1_0 : hs == 1 ? t1_1 : hs == 2 ? t1_2 : t1_3;
    float u2 = hs == 0 ? t2_0 : hs == 1 ? t2_1 : hs == 2 ? t2_2 : t2_3;
    float dsv = hs == 0 ? ds_0 : hs == 1 ? ds_1 : hs == 2 ? ds_2 : ds_3;
    float ui = 1.f / fmaxf(dsv, 1e-16f);

    __syncthreads();  // weight staging complete; orders shx below
    int f0 = g * 8;
#pragma unroll
    for (int j = 0; j < 8; ++j) {
        int f = f0 + j;
        float o = fmaf(fmaf(u0, sW1[f], fmaf(u1, sW1[128 + f], u2 * sW1[256 + f])), ui, sb1[f]);
        shx[nl][f] = (o > 0.f) ? o : __expf(o) - 1.f;  // ELU
    }
    __syncthreads();

    // W2 matmul: thread (nl, c) -> h2w[n, c]; + alpha2 reduce
    int c = g;
    const float4* hr4 = (const float4*)shx[nl];
    float acc = 0.f;
#pragma unroll 8
    for (int k4 = 0; k4 < 32; ++k4) {
        float4 hv = hr4[k4];
        acc = fmaf(hv.x, sW2[(k4 * 4 + 0) * 16 + c], acc);
        acc = fmaf(hv.y, sW2[(k4 * 4 + 1) * 16 + c], acc);
        acc = fmaf(hv.z, sW2[(k4 * 4 + 2) * 16 + c], acc);
        acc = fmaf(hv.w, sW2[(k4 * 4 + 3) * 16 + c], acc);
    }
    if (n < N) {
        h2w[(size_t)n * 16 + c] = acc;
        float ps = acc * aws2[c];
        float pd = acc * awd2[c];
#pragma unroll
        for (int m = 1; m < 16; m <<= 1) {
            ps += __shfl_xor(ps, m);
            pd += __shfl_xor(pd, m);
        }
        if (c == 0) {
            as2[n] = ps;
            ad2[n] = pd;
        }
    }
}

// ---------------------------------------------------------------------------
// Layer-2 softmax+aggregate -> d_out. 16 lanes/node (slot(4) x c-quad(4)),
// single pass (no max), 16 nodes per 256-thread block. Edge loop pipelined
// 2-wide (dual independent gather chains).
__global__ void __launch_bounds__(256) k_gat2(const float* __restrict__ h2w,
                                              const float* __restrict__ as2,
                                              const float* __restrict__ ad2,
                                              const int* __restrict__ beg,
                                              const int* __restrict__ endo,
                                              const int* __restrict__ ssrc,
                                              const float* __restrict__ b2,
                                              float* __restrict__ out, int N) {
    int t = threadIdx.x;
    int nl = t >> 4, g = t & 15;
    int n = blockIdx.x * 16 + nl;
    if (n >= N) return;
    int slot = g >> 2, c4 = g & 3;
    int e0 = beg[n], e1 = endo[n];
    float ad = ad2[n];

    float4 acc = {0.f, 0.f, 0.f, 0.f};
    float ds = 0.f;
    for (int e = e0 + slot; e < e1; e += 8) {
        int sA = ssrc[e];
        bool vB = (e + 4) < e1;
        int sB = vB ? ssrc[e + 4] : sA;
        float aA = as2[sA];
        float aB = as2[sB];
        const float4 hA = *(const float4*)(h2w + (size_t)sA * 16 + c4 * 4);
        const float4 hB = *(const float4*)(h2w + (size_t)sB * 16 + c4 * 4);
        float wA = __expf(LRELU(aA + ad));
        float wB = vB ? __expf(LRELU(aB + ad)) : 0.f;
        ds += wA + wB;
        acc.x = fmaf(wA, hA.x, fmaf(wB, hB.x, acc.x));
        acc.y = fmaf(wA, hA.y, fmaf(wB, hB.y, acc.y));
        acc.z = fmaf(wA, hA.z, fmaf(wB, hB.z, acc.z));
        acc.w = fmaf(wA, hA.w, fmaf(wB, hB.w, acc.w));
    }
#pragma unroll
    for (int msk = 4; msk < 16; msk <<= 1) {
        acc.x += __shfl_xor(acc.x, msk);
        acc.y += __shfl_xor(acc.y, msk);
        acc.z += __shfl_xor(acc.z, msk);
        acc.w += __shfl_xor(acc.w, msk);
        ds += __shfl_xor(ds, msk);
    }
    if (slot == 0) {
        float inv = 1.f / fmaxf(ds, 1e-16f);
        float4 bq = ((const float4*)b2)[c4];
        float4 o;
        o.x = fmaf(acc.x, inv, bq.x);
        o.y = fmaf(acc.y, inv, bq.y);
        o.z = fmaf(acc.z, inv, bq.z);
        o.w = fmaf(acc.w, inv, bq.w);
        *(float4*)(out + (size_t)n * 16 + c4 * 4) = o;
    }
}

// ---------------------------------------------------------------------------
extern "C" void kernel_launch(void* const* d_in, const int* in_sizes, int n_in,
                              void* d_out, int out_size, void* d_ws, size_t ws_size,
                              hipStream_t stream) {
    const float* x    = (const float*)d_in[0];
    const int*   ei   = (const int*)d_in[1];
    const float* W1   = (const float*)d_in[2];
    const float* aws1 = (const float*)d_in[3];
    const float* awd1 = (const float*)d_in[4];
    const float* b1   = (const float*)d_in[5];
    const float* W2   = (const float*)d_in[6];
    const float* aws2 = (const float*)d_in[7];
    const float* awd2 = (const float*)d_in[8];
    const float* b2   = (const float*)d_in[9];
    float* out = (float*)d_out;

    const int N = in_sizes[0] / 3;            // 50000
    const long long E = in_sizes[1] / 2;      // 1600000
    const int NB = (N + 127) / 128;           // 391 dst-buckets

    char* w = (char*)d_ws;
    auto alloc = [&](size_t bytes) {
        char* p = w;
        w += (bytes + 255) & ~(size_t)255;
        return p;
    };
    float*    rec    = (float*)alloc((size_t)N * 8 * 4);        // {as1[4], x0,x1,x2,pad}
    float*    ad1    = (float*)alloc((size_t)N * 4 * 4);
    float*    h2w    = (float*)alloc((size_t)N * 16 * 4);
    float*    as2    = (float*)alloc((size_t)N * 4);
    float*    ad2    = (float*)alloc((size_t)N * 4);
    int*      beg    = (int*)alloc((size_t)N * 4);
    int*      endo   = (int*)alloc((size_t)N * 4);
    int*      ssrc   = (int*)alloc((size_t)NB * WCAP * 4);      // padded windows
    unsigned* bstage = (unsigned*)alloc((size_t)NB * BCAP * 4); // padded windows
    int*      gcur   = (int*)alloc((size_t)NB * 4);
    int*      flag   = (int*)alloc(4);

    // 1) h1 records (+ gcur init + dtype probe in block 0)
    k_h1<<<(N + 1) / 2, 256, 0, stream>>>(x, W1, aws1, awd1, ei, rec, ad1,
                                          gcur, flag, NB, N);
    // 2) single-pass multisplit into fixed bucket windows
    k_msplit<<<(int)((E + MS_CHUNK - 1) / MS_CHUNK), 256, 0, stream>>>(ei, E, flag, gcur, bstage);
    // 3) per-bucket CSR build (beg/end + ssrc)
    k_bucket<<<NB, 256, 0, stream>>>(bstage, gcur, beg, endo, ssrc, N);
    // 4) fused layer-1 aggregate + W1 expand + ELU + W2 + alpha2 (pipelined)
    k_gat1w<<<(N + 15) / 16, 256, 0, stream>>>(rec, ad1, beg, endo, ssrc, W1, b1,
                                               W2, aws2, awd2, h2w, as2, ad2, N);
    // 5) layer-2 aggregate -> out (pipelined)
    k_gat2<<<(N + 15) / 16, 256, 0, stream>>>(h2w, as2, ad2, beg, endo, ssrc, b2, out, N);
}